// Round 1
// baseline (1422.628 us; speedup 1.0000x reference)
//
#include <hip/hip_runtime.h>
#include <stdint.h>
#include <math.h>

// Problem constants (B,H,SQ,SK,D,DV) = (2,16,2048,2048,64,64)
// probs = softmax(qk) * (1/2); dropout p=0.1, jax threefry key 42 (partitionable layout)
namespace {
constexpr int Bb = 2, Hh = 16, SQc = 2048, SKc = 2048, Dc = 64, DVc = 64;
constexpr int TQ = 64, TK = 64;
constexpr int NKT = SKc / TK;         // 32 k-tiles
constexpr int QSTR = 68;              // Qs row stride (floats), 16B-aligned, bank-spread
constexpr int KSTR = 68;              // Kt row stride (d-major)
constexpr int VSTR = 64;              // Vs row stride
constexpr int PSTR = 68;              // Ps row stride (union with Kt)

// JAX threefry2x32, key = (0, 42). Partitionable 32-bit path:
// bits(i) = o0 ^ o1 of threefry((0,42), (0, i)).  keep = bits < 0xE6666600
// (exact integer form of uniform(bits) < 0.9f).
__device__ __forceinline__ uint32_t tf_bits(uint32_t ctr) {
  const uint32_t ks0 = 0u;
  const uint32_t ks1 = 42u;
  const uint32_t ks2 = 0x1BD11BDAu ^ 0u ^ 42u;  // 0x1BD11BF0
  uint32_t x0 = ks0;        // counts_hi (=0) + ks0
  uint32_t x1 = ctr + ks1;  // counts_lo + ks1
#define TFR(r) { x0 += x1; x1 = (x1 << (r)) | (x1 >> (32 - (r))); x1 ^= x0; }
  TFR(13) TFR(15) TFR(26) TFR(6)
  x0 += ks1; x1 += ks2 + 1u;
  TFR(17) TFR(29) TFR(16) TFR(24)
  x0 += ks2; x1 += ks0 + 2u;
  TFR(13) TFR(15) TFR(26) TFR(6)
  x0 += ks0; x1 += ks1 + 3u;
  TFR(17) TFR(29) TFR(16) TFR(24)
  x0 += ks1; x1 += ks2 + 4u;
  TFR(13) TFR(15) TFR(26) TFR(6)
  x0 += ks2; x1 += ks0 + 5u;
#undef TFR
  return x0 ^ x1;
}
}  // namespace

__global__ __launch_bounds__(256) void attn_drop_kernel(
    const float* __restrict__ q, const float* __restrict__ k,
    const float* __restrict__ v, float* __restrict__ out) {
  __shared__ float Qs[TQ * QSTR];  // 17408 B, Q tile row-major
  __shared__ float KP[TK * KSTR];  // 17408 B, union: Kt (d-major) then Ps
  __shared__ float Vs[TK * VSTR];  // 16384 B, V tile row-major
  // total 50 KB -> 3 blocks/CU by LDS

  const int t = threadIdx.x;
  const int tx = t & 15;    // 16 column-groups (4 cols each)
  const int ty = t >> 4;    // 16 row-groups (4 rows each)
  const int blk = blockIdx.x;
  const int qt = blk & 31;          // q-tile varies fastest -> same-h blocks share K/V in L2
  const int h = (blk >> 5) & 15;
  const int b = blk >> 9;
  const int q0 = qt * TQ;

  const float* qbase = q + (((size_t)(b * Hh + h)) * SQc + q0) * Dc;
  const float* kbase = k + (size_t)h * SKc * Dc;
  const float* vbase = v + (size_t)h * SKc * DVc;

  // ---- load Q tile (64x64 floats, coalesced float4) ----
#pragma unroll
  for (int i = 0; i < 4; ++i) {
    int f = t + 256 * i;             // float4 id 0..1023
    int row = f >> 4;
    int d0 = (f & 15) << 2;
    float4 qv = *(const float4*)(qbase + row * Dc + d0);
    *(float4*)(&Qs[row * QSTR + d0]) = qv;
  }

  float acc[4][4] = {};
  float m_i[4], l_i[4];
#pragma unroll
  for (int r = 0; r < 4; ++r) { m_i[r] = -INFINITY; l_i[r] = 0.f; }

  for (int kt = 0; kt < NKT; ++kt) {
    __syncthreads();  // prev tile's PV reads of KP/Vs done (also orders first Q load)
    // ---- stage K (transposed -> Kt[d][j]) and V (row-major) ----
#pragma unroll
    for (int i = 0; i < 4; ++i) {
      int f = t + 256 * i;
      int row = f >> 4;
      int d0 = (f & 15) << 2;
      float4 kv = *(const float4*)(kbase + (size_t)(kt * TK + row) * Dc + d0);
      KP[(d0 + 0) * KSTR + row] = kv.x;
      KP[(d0 + 1) * KSTR + row] = kv.y;
      KP[(d0 + 2) * KSTR + row] = kv.z;
      KP[(d0 + 3) * KSTR + row] = kv.w;
      float4 vv = *(const float4*)(vbase + (size_t)(kt * TK + row) * DVc + d0);
      *(float4*)(&Vs[row * VSTR + d0]) = vv;
    }
    __syncthreads();

    // ---- S = Q . K^T : thread owns rows i=ty*4+r, cols j=tx*4+c ----
    float s[4][4] = {};
#pragma unroll
    for (int d0 = 0; d0 < Dc; d0 += 4) {
      float4 qv[4], kv[4];
#pragma unroll
      for (int r = 0; r < 4; ++r)
        qv[r] = *(const float4*)(&Qs[(ty * 4 + r) * QSTR + d0]);
#pragma unroll
      for (int dd = 0; dd < 4; ++dd)
        kv[dd] = *(const float4*)(&KP[(d0 + dd) * KSTR + tx * 4]);
#pragma unroll
      for (int r = 0; r < 4; ++r) {
        s[r][0] += qv[r].x * kv[0].x + qv[r].y * kv[1].x + qv[r].z * kv[2].x + qv[r].w * kv[3].x;
        s[r][1] += qv[r].x * kv[0].y + qv[r].y * kv[1].y + qv[r].z * kv[2].y + qv[r].w * kv[3].y;
        s[r][2] += qv[r].x * kv[0].z + qv[r].y * kv[1].z + qv[r].z * kv[2].z + qv[r].w * kv[3].z;
        s[r][3] += qv[r].x * kv[0].w + qv[r].y * kv[1].w + qv[r].z * kv[2].w + qv[r].w * kv[3].w;
      }
    }
    __syncthreads();  // all Kt reads done -> KP reusable as Ps

    // ---- online softmax (rows replicated across the 16 tx lanes) ----
    float pj[4][4];
#pragma unroll
    for (int r = 0; r < 4; ++r) {
      float mt = fmaxf(fmaxf(s[r][0], s[r][1]), fmaxf(s[r][2], s[r][3]));
      mt = fmaxf(mt, __shfl_xor(mt, 1));
      mt = fmaxf(mt, __shfl_xor(mt, 2));
      mt = fmaxf(mt, __shfl_xor(mt, 4));
      mt = fmaxf(mt, __shfl_xor(mt, 8));
      float mnew = fmaxf(m_i[r], mt);
      float alpha = __expf(m_i[r] - mnew);
      float rs = 0.f;
#pragma unroll
      for (int c = 0; c < 4; ++c) { pj[r][c] = __expf(s[r][c] - mnew); rs += pj[r][c]; }
      rs += __shfl_xor(rs, 1);
      rs += __shfl_xor(rs, 2);
      rs += __shfl_xor(rs, 4);
      rs += __shfl_xor(rs, 8);
      l_i[r] = l_i[r] * alpha + rs;  // denominator: UNdropped probs
      m_i[r] = mnew;
#pragma unroll
      for (int c = 0; c < 4; ++c) acc[r][c] *= alpha;
    }

    // ---- dropout on numerator + write P tile ----
#pragma unroll
    for (int r = 0; r < 4; ++r) {
      const uint32_t rowflat =
          ((uint32_t)((b * Hh + h) * SQc) + (uint32_t)(q0 + ty * 4 + r)) * (uint32_t)SKc;
      const uint32_t cbase = rowflat + (uint32_t)(kt * TK + tx * 4);
#pragma unroll
      for (int c = 0; c < 4; ++c) {
        uint32_t bits = tf_bits(cbase + (uint32_t)c);
        if (bits >= 0xE6666600u) pj[r][c] = 0.f;  // dropped
      }
      *(float4*)(&KP[(ty * 4 + r) * PSTR + tx * 4]) =
          make_float4(pj[r][0], pj[r][1], pj[r][2], pj[r][3]);
    }
    __syncthreads();  // Ps ready

    // ---- acc += P . V : thread owns rows i=ty*4+r, out cols c=tx*4.. ----
#pragma unroll
    for (int j0 = 0; j0 < TK; j0 += 4) {
      float4 pv[4], vv[4];
#pragma unroll
      for (int r = 0; r < 4; ++r)
        pv[r] = *(const float4*)(&KP[(ty * 4 + r) * PSTR + j0]);
#pragma unroll
      for (int u = 0; u < 4; ++u)
        vv[u] = *(const float4*)(&Vs[(j0 + u) * VSTR + tx * 4]);
#pragma unroll
      for (int r = 0; r < 4; ++r) {
        acc[r][0] += pv[r].x * vv[0].x + pv[r].y * vv[1].x + pv[r].z * vv[2].x + pv[r].w * vv[3].x;
        acc[r][1] += pv[r].x * vv[0].y + pv[r].y * vv[1].y + pv[r].z * vv[2].y + pv[r].w * vv[3].y;
        acc[r][2] += pv[r].x * vv[0].z + pv[r].y * vv[1].z + pv[r].z * vv[2].z + pv[r].w * vv[3].z;
        acc[r][3] += pv[r].x * vv[0].w + pv[r].y * vv[1].w + pv[r].z * vv[2].w + pv[r].w * vv[3].w;
      }
    }
  }

  // ---- epilogue: out = acc * (inv_scale / (keep_prob * l)) ----
  float* obase = out + (((size_t)(b * Hh + h)) * SQc + q0) * DVc;
#pragma unroll
  for (int r = 0; r < 4; ++r) {
    int row = ty * 4 + r;
    float sc = (0.5f / 0.9f) / l_i[r];
    float4 o = make_float4(acc[r][0] * sc, acc[r][1] * sc, acc[r][2] * sc, acc[r][3] * sc);
    *(float4*)(obase + row * DVc + tx * 4) = o;
  }
}

extern "C" void kernel_launch(void* const* d_in, const int* in_sizes, int n_in,
                              void* d_out, int out_size, void* d_ws, size_t ws_size,
                              hipStream_t stream) {
  const float* q = (const float*)d_in[0];
  const float* k = (const float*)d_in[1];
  const float* v = (const float*)d_in[2];
  float* out = (float*)d_out;
  dim3 grid(Bb * Hh * (SQc / TQ));  // 1024 blocks
  attn_drop_kernel<<<grid, 256, 0, stream>>>(q, k, v, out);
}

// Round 2
// 462.666 us; speedup vs baseline: 3.0748x; 3.0748x over previous
//
#include <hip/hip_runtime.h>
#include <stdint.h>
#include <math.h>

// (B,H,SQ,SK,D,DV) = (2,16,2048,2048,64,64)
// out = softmax(q k^T) * 0.5, dropout p=0.1 (jax threefry key 42, partitionable), @ v
// R2: MFMA 16x16x32 bf16 for QK^T (3-term split bf16 for fp32-level accuracy) and PV.
namespace {
constexpr int Bb = 2, Hh = 16, SQc = 2048, SKc = 2048, Dc = 64, DVc = 64;
constexpr int TQ = 64, TK = 64;
constexpr int NKT = SKc / TK;   // 32 k-tiles
constexpr int STR = 72;         // bf16 row stride: 144B = 16B-aligned, +4 banks/row (2-way = free)

typedef __attribute__((ext_vector_type(8))) short short8;   // MFMA A/B frag (8 bf16)
typedef __attribute__((ext_vector_type(4))) float f32x4;    // MFMA C/D frag

// JAX threefry2x32, key=(0,42), partitionable: bits(i) = o0^o1 of threefry((0,42),(0,i)).
// keep iff bits < 0xE6666600 (exact integer form of uniform(bits) < 0.9f). VERIFIED R1.
__device__ __forceinline__ uint32_t tf_bits(uint32_t ctr) {
  const uint32_t ks0 = 0u, ks1 = 42u, ks2 = 0x1BD11BDAu ^ 42u;
  uint32_t x0 = ks0;
  uint32_t x1 = ctr + ks1;
#define TFR(r) { x0 += x1; x1 = (x1 << (r)) | (x1 >> (32 - (r))); x1 ^= x0; }
  TFR(13) TFR(15) TFR(26) TFR(6)
  x0 += ks1; x1 += ks2 + 1u;
  TFR(17) TFR(29) TFR(16) TFR(24)
  x0 += ks2; x1 += ks0 + 2u;
  TFR(13) TFR(15) TFR(26) TFR(6)
  x0 += ks0; x1 += ks1 + 3u;
  TFR(17) TFR(29) TFR(16) TFR(24)
  x0 += ks1; x1 += ks2 + 4u;
  TFR(13) TFR(15) TFR(26) TFR(6)
  x0 += ks2; x1 += ks0 + 5u;
#undef TFR
  return x0 ^ x1;
}

__device__ __forceinline__ uint16_t f2bf(float x) {   // RNE, matches HW cvt for finite x
  uint32_t u = __float_as_uint(x);
  u += 0x7FFFu + ((u >> 16) & 1u);
  return (uint16_t)(u >> 16);
}
__device__ __forceinline__ float bf2f(uint16_t h) {
  return __uint_as_float(((uint32_t)h) << 16);
}
}  // namespace

__global__ __launch_bounds__(256, 3) void attn_mfma_kernel(
    const float* __restrict__ q, const float* __restrict__ k,
    const float* __restrict__ v, float* __restrict__ out) {
  // 4 x 9216 B = 36864 B LDS
  __shared__ __align__(16) unsigned short Kh[TK * STR];  // K tile hi-bf16 (row-major); Q-hi transient
  __shared__ __align__(16) unsigned short Kl[TK * STR];  // K tile lo-residual;        Q-lo transient
  __shared__ __align__(16) unsigned short Vt[DVc * STR]; // V^T tile: Vt[dv][sk]
  __shared__ __align__(16) unsigned short Pb[TQ * STR];  // P tile bf16 (row-major)

  const int t = threadIdx.x;
  const int lane = t & 63;
  const int w = t >> 6;          // wave 0..3, owns q-rows w*16..w*16+15
  const int lm = lane & 15;      // MFMA m/n index
  const int quad = lane >> 4;    // MFMA k-group / row-quad

  // XCD swizzle: blocks of same (b,h) grouped per XCD (L2 locality for K/V)
  const int blk = blockIdx.x;
  const int vid = (blk & 7) * 128 + (blk >> 3);
  const int qt = vid & 31;
  const int h = (vid >> 5) & 15;
  const int b = vid >> 9;
  const int q0 = qt * TQ;

  const float* qbase = q + (((size_t)(b * Hh + h)) * SQc + q0) * Dc;
  const float* kbase = k + (size_t)h * SKc * Dc;
  const float* vbase = v + (size_t)h * SKc * DVc;

  // ---- stage Q tile split-bf16 into Kh/Kl (transient), coalesced float4 ----
#pragma unroll
  for (int i = 0; i < 4; ++i) {
    int f = t + 256 * i;
    int row = f >> 4, d0 = (f & 15) << 2;
    float4 qv = *(const float4*)(qbase + row * Dc + d0);
    uint16_t h0 = f2bf(qv.x), h1 = f2bf(qv.y), h2 = f2bf(qv.z), h3 = f2bf(qv.w);
    uint16_t l0 = f2bf(qv.x - bf2f(h0)), l1 = f2bf(qv.y - bf2f(h1));
    uint16_t l2 = f2bf(qv.z - bf2f(h2)), l3 = f2bf(qv.w - bf2f(h3));
    ushort4 ph = make_ushort4(h0, h1, h2, h3);
    ushort4 pl = make_ushort4(l0, l1, l2, l3);
    *(ushort4*)&Kh[row * STR + d0] = ph;
    *(ushort4*)&Kl[row * STR + d0] = pl;
  }
  __syncthreads();

  // Q A-frags to registers (constant across k-loop): A[m=lm][k=quad*8+j], chunks k0=0,32
  short8 qh[2], ql[2];
  {
    int row = w * 16 + lm;
    qh[0] = *(const short8*)&Kh[row * STR + 0 + quad * 8];
    qh[1] = *(const short8*)&Kh[row * STR + 32 + quad * 8];
    ql[0] = *(const short8*)&Kl[row * STR + 0 + quad * 8];
    ql[1] = *(const short8*)&Kl[row * STR + 32 + quad * 8];
  }

  f32x4 acc[4] = {{0.f, 0.f, 0.f, 0.f}, {0.f, 0.f, 0.f, 0.f},
                  {0.f, 0.f, 0.f, 0.f}, {0.f, 0.f, 0.f, 0.f}};
  float m_i[4], l_i[4];
#pragma unroll
  for (int r = 0; r < 4; ++r) { m_i[r] = -INFINITY; l_i[r] = 0.f; }

  for (int kt = 0; kt < NKT; ++kt) {
    __syncthreads();  // prior-iter frag reads (and initial Q frag reads) complete

    // ---- stage K split-bf16 (row-major) ----
#pragma unroll
    for (int i = 0; i < 4; ++i) {
      int f = t + 256 * i;
      int row = f >> 4, d0 = (f & 15) << 2;
      float4 kv = *(const float4*)(kbase + (size_t)(kt * TK + row) * Dc + d0);
      uint16_t h0 = f2bf(kv.x), h1 = f2bf(kv.y), h2 = f2bf(kv.z), h3 = f2bf(kv.w);
      uint16_t l0 = f2bf(kv.x - bf2f(h0)), l1 = f2bf(kv.y - bf2f(h1));
      uint16_t l2 = f2bf(kv.z - bf2f(h2)), l3 = f2bf(kv.w - bf2f(h3));
      *(ushort4*)&Kh[row * STR + d0] = make_ushort4(h0, h1, h2, h3);
      *(ushort4*)&Kl[row * STR + d0] = make_ushort4(l0, l1, l2, l3);
    }
    // ---- stage V transposed: each thread transposes one 4x4 block ----
    {
      int r0 = (t >> 4) << 2;   // sk 0..60
      int d0 = (t & 15) << 2;   // dv 0..60
      uint16_t tb[4][4];
#pragma unroll
      for (int i = 0; i < 4; ++i) {
        float4 vv = *(const float4*)(vbase + (size_t)(kt * TK + r0 + i) * DVc + d0);
        tb[0][i] = f2bf(vv.x); tb[1][i] = f2bf(vv.y);
        tb[2][i] = f2bf(vv.z); tb[3][i] = f2bf(vv.w);
      }
#pragma unroll
      for (int j = 0; j < 4; ++j)
        *(ushort4*)&Vt[(d0 + j) * STR + r0] =
            make_ushort4(tb[j][0], tb[j][1], tb[j][2], tb[j][3]);
    }
    __syncthreads();

    // ---- S = Q K^T via MFMA; 3-term split: qh*kh + qh*kl + ql*kh ----
    f32x4 s[4];
#pragma unroll
    for (int nb = 0; nb < 4; ++nb) {
      f32x4 cs = {0.f, 0.f, 0.f, 0.f};
      int krow = nb * 16 + lm;  // B-frag: lane n reads K row n, 8 contiguous d
#pragma unroll
      for (int c = 0; c < 2; ++c) {
        short8 khf = *(const short8*)&Kh[krow * STR + c * 32 + quad * 8];
        short8 klf = *(const short8*)&Kl[krow * STR + c * 32 + quad * 8];
        cs = __builtin_amdgcn_mfma_f32_16x16x32_bf16(qh[c], khf, cs, 0, 0, 0);
        cs = __builtin_amdgcn_mfma_f32_16x16x32_bf16(qh[c], klf, cs, 0, 0, 0);
        cs = __builtin_amdgcn_mfma_f32_16x16x32_bf16(ql[c], khf, cs, 0, 0, 0);
      }
      s[nb] = cs;
    }

    // ---- online softmax; C-layout: row = quad*4+r, col = nb*16+lm ----
    float pj[4][4];  // [nb][r]
#pragma unroll
    for (int r = 0; r < 4; ++r) {
      float mt = fmaxf(fmaxf(s[0][r], s[1][r]), fmaxf(s[2][r], s[3][r]));
      mt = fmaxf(mt, __shfl_xor(mt, 1));
      mt = fmaxf(mt, __shfl_xor(mt, 2));
      mt = fmaxf(mt, __shfl_xor(mt, 4));
      mt = fmaxf(mt, __shfl_xor(mt, 8));
      float mnew = fmaxf(m_i[r], mt);
      float alpha = __expf(m_i[r] - mnew);
      float rs = 0.f;
#pragma unroll
      for (int nb = 0; nb < 4; ++nb) { pj[nb][r] = __expf(s[nb][r] - mnew); rs += pj[nb][r]; }
      rs += __shfl_xor(rs, 1);
      rs += __shfl_xor(rs, 2);
      rs += __shfl_xor(rs, 4);
      rs += __shfl_xor(rs, 8);
      l_i[r] = l_i[r] * alpha + rs;  // denominator over UNdropped probs
      m_i[r] = mnew;
#pragma unroll
      for (int nb = 0; nb < 4; ++nb) acc[nb][r] *= alpha;
    }

    // ---- dropout (threefry) + store P tile bf16 ----
    {
      const uint32_t rb = (uint32_t)((b * Hh + h) * SQc + q0 + w * 16 + quad * 4);
#pragma unroll
      for (int r = 0; r < 4; ++r) {
        uint32_t cb = (rb + r) * (uint32_t)SKc + (uint32_t)(kt * TK) + (uint32_t)lm;
        int prow = w * 16 + quad * 4 + r;
#pragma unroll
        for (int nb = 0; nb < 4; ++nb) {
          uint32_t bits = tf_bits(cb + (uint32_t)(nb * 16));
          float p = (bits < 0xE6666600u) ? pj[nb][r] : 0.f;
          Pb[prow * STR + nb * 16 + lm] = f2bf(p);
        }
      }
    }
    __syncthreads();

    // ---- O += P V via MFMA: A = P rows, B = V^T rows ----
    {
      int prow = w * 16 + lm;
      short8 pa0 = *(const short8*)&Pb[prow * STR + 0 + quad * 8];
      short8 pa1 = *(const short8*)&Pb[prow * STR + 32 + quad * 8];
#pragma unroll
      for (int nb = 0; nb < 4; ++nb) {
        int vrow = nb * 16 + lm;
        short8 vb0 = *(const short8*)&Vt[vrow * STR + 0 + quad * 8];
        short8 vb1 = *(const short8*)&Vt[vrow * STR + 32 + quad * 8];
        acc[nb] = __builtin_amdgcn_mfma_f32_16x16x32_bf16(pa0, vb0, acc[nb], 0, 0, 0);
        acc[nb] = __builtin_amdgcn_mfma_f32_16x16x32_bf16(pa1, vb1, acc[nb], 0, 0, 0);
      }
    }
  }

  // ---- epilogue: out = acc * (0.5/0.9) / l ----
  float* obase = out + (((size_t)(b * Hh + h)) * SQc + q0) * DVc;
#pragma unroll
  for (int r = 0; r < 4; ++r) {
    int row = w * 16 + quad * 4 + r;
    float sc = (0.5f / 0.9f) / l_i[r];
#pragma unroll
    for (int nb = 0; nb < 4; ++nb)
      obase[(size_t)row * DVc + nb * 16 + lm] = acc[nb][r] * sc;
  }
}

extern "C" void kernel_launch(void* const* d_in, const int* in_sizes, int n_in,
                              void* d_out, int out_size, void* d_ws, size_t ws_size,
                              hipStream_t stream) {
  const float* q = (const float*)d_in[0];
  const float* k = (const float*)d_in[1];
  const float* v = (const float*)d_in[2];
  float* out = (float*)d_out;
  dim3 grid(Bb * Hh * (SQc / TQ));  // 1024 blocks, 4/CU
  attn_mfma_kernel<<<grid, 256, 0, stream>>>(q, k, v, out);
}

// Round 3
// 450.494 us; speedup vs baseline: 3.1579x; 1.0270x over previous
//
#include <hip/hip_runtime.h>
#include <stdint.h>
#include <math.h>

// (B,H,SQ,SK,D,DV) = (2,16,2048,2048,64,64)
// out = (softmax(q k^T) * 0.5) with dropout p=0.1 (jax threefry key 42, partitionable) @ v
// R3: S^T/O^T formulation -> zero LDS / zero barriers in k-loop; K/V pre-converted
// to bf16 (split) by a pre-pass; P transposed C-layout->B-frag via ds_bpermute.
namespace {
constexpr int Bb = 2, Hh = 16, SQc = 2048, SKc = 2048, Dc = 64, DVc = 64;
constexpr int TQ = 64, TK = 64;
constexpr int NKT = SKc / TK;

typedef __attribute__((ext_vector_type(8))) short short8;   // MFMA A/B frag (8 bf16)
typedef __attribute__((ext_vector_type(4))) float f32x4;    // MFMA C/D frag

// JAX threefry2x32, key=(0,42), partitionable: bits(i)=o0^o1 of threefry((0,42),(0,i)).
// keep iff bits < 0xE6666600 (exact integer form of uniform(bits) < 0.9f). VERIFIED R1/R2.
__device__ __forceinline__ uint32_t tf_bits(uint32_t ctr) {
  const uint32_t ks0 = 0u, ks1 = 42u, ks2 = 0x1BD11BDAu ^ 42u;
  uint32_t x0 = ks0;
  uint32_t x1 = ctr + ks1;
#define TFR(r) { x0 += x1; x1 = (x1 << (r)) | (x1 >> (32 - (r))); x1 ^= x0; }
  TFR(13) TFR(15) TFR(26) TFR(6)
  x0 += ks1; x1 += ks2 + 1u;
  TFR(17) TFR(29) TFR(16) TFR(24)
  x0 += ks2; x1 += ks0 + 2u;
  TFR(13) TFR(15) TFR(26) TFR(6)
  x0 += ks0; x1 += ks1 + 3u;
  TFR(17) TFR(29) TFR(16) TFR(24)
  x0 += ks1; x1 += ks2 + 4u;
  TFR(13) TFR(15) TFR(26) TFR(6)
  x0 += ks2; x1 += ks0 + 5u;
#undef TFR
  return x0 ^ x1;
}

__device__ __forceinline__ uint32_t f2bf_u(float x) {  // RNE bf16 (finite x), low 16 bits
  uint32_t u = __float_as_uint(x);
  u += 0x7FFFu + ((u >> 16) & 1u);
  return u >> 16;
}
}  // namespace

// Pre-pass: K -> Kh (bf16 hi) + Kl (bf16 residual), row-major [h][sk][d];
//           V -> Vt bf16 transposed [h][dv][sk].
__global__ __launch_bounds__(256) void prep_kernel(
    const float* __restrict__ k, const float* __restrict__ v,
    unsigned short* __restrict__ Khg, unsigned short* __restrict__ Klg,
    unsigned short* __restrict__ Vtg) {
  __shared__ float Vs[64 * 65];
  const int t = threadIdx.x;
  const int h = blockIdx.x >> 5;
  const int skt = blockIdx.x & 31;
  const size_t base = ((size_t)h * SKc + skt * 64) * Dc;
#pragma unroll
  for (int i = 0; i < 4; ++i) {
    int idx = t + 256 * i;
    int row = idx >> 4, d0 = (idx & 15) << 2;
    float4 kv = *(const float4*)(k + base + row * Dc + d0);
    uint32_t hx = f2bf_u(kv.x), hy = f2bf_u(kv.y), hz = f2bf_u(kv.z), hw = f2bf_u(kv.w);
    uint32_t lx = f2bf_u(kv.x - __uint_as_float(hx << 16));
    uint32_t ly = f2bf_u(kv.y - __uint_as_float(hy << 16));
    uint32_t lz = f2bf_u(kv.z - __uint_as_float(hz << 16));
    uint32_t lw = f2bf_u(kv.w - __uint_as_float(hw << 16));
    *(ushort4*)(Khg + base + row * Dc + d0) =
        make_ushort4((unsigned short)hx, (unsigned short)hy, (unsigned short)hz, (unsigned short)hw);
    *(ushort4*)(Klg + base + row * Dc + d0) =
        make_ushort4((unsigned short)lx, (unsigned short)ly, (unsigned short)lz, (unsigned short)lw);
    float4 vv = *(const float4*)(v + base + row * Dc + d0);  // DVc == Dc
    *(float4*)(&Vs[row * 65 + d0]) = vv;
  }
  __syncthreads();
  const int dv = t >> 2, sk0 = (t & 3) << 4;
  unsigned short tmp[16];
#pragma unroll
  for (int j = 0; j < 16; ++j) tmp[j] = (unsigned short)f2bf_u(Vs[(sk0 + j) * 65 + dv]);
  unsigned short* vp = Vtg + ((size_t)h * DVc + dv) * SKc + skt * 64 + sk0;
  *(short8*)(vp) = *(const short8*)&tmp[0];
  *(short8*)(vp + 8) = *(const short8*)&tmp[8];
}

__global__ __launch_bounds__(256, 4) void attn_main(
    const float* __restrict__ q, const unsigned short* __restrict__ Khg,
    const unsigned short* __restrict__ Klg, const unsigned short* __restrict__ Vtg,
    float* __restrict__ out) {
  const int t = threadIdx.x;
  const int lane = t & 63;
  const int w = t >> 6;          // wave: q-rows w*16..w*16+15 (one row per lm)
  const int lm = lane & 15;
  const int quad = lane >> 4;

  // XCD swizzle: same-(b,h) blocks grouped per XCD for K/V L2 locality
  const int vid = (blockIdx.x & 7) * 128 + (blockIdx.x >> 3);
  const int qt = vid & 31;
  const int h = (vid >> 5) & 15;
  const int b = vid >> 9;
  const int q0 = qt * TQ;
  const int qrow = q0 + w * 16 + lm;

  // ---- Q B-frags (fp32 -> split bf16 in regs), constant over k-loop ----
  short8 qh[2], ql[2];
  {
    const float* qp = q + (((size_t)(b * Hh + h)) * SQc + qrow) * Dc;
#pragma unroll
    for (int c = 0; c < 2; ++c) {
      float x[8];
      *(float4*)&x[0] = *(const float4*)(qp + c * 32 + quad * 8);
      *(float4*)&x[4] = *(const float4*)(qp + c * 32 + quad * 8 + 4);
#pragma unroll
      for (int j = 0; j < 8; ++j) {
        uint32_t hb = f2bf_u(x[j]);
        float lo = x[j] - __uint_as_float(hb << 16);
        qh[c][j] = (short)hb;
        ql[c][j] = (short)f2bf_u(lo);
      }
    }
  }

  const unsigned short* kh_base = Khg + (size_t)h * SKc * Dc;
  const unsigned short* kl_base = Klg + (size_t)h * SKc * Dc;
  const unsigned short* vt_base = Vtg + (size_t)h * DVc * SKc;

  f32x4 acc[4] = {{0.f, 0.f, 0.f, 0.f}, {0.f, 0.f, 0.f, 0.f},
                  {0.f, 0.f, 0.f, 0.f}, {0.f, 0.f, 0.f, 0.f}};
  float m_i = -INFINITY, l_i = 0.f;

  // bpermute byte-addresses for the cross-quad P exchange (constant per lane)
  const int a0 = ((quad & 1) * 32 + lm) << 2;  // src quad 2*(quad&1), j=0..3
  const int a1 = a0 + 64;                      // src quad 2*(quad&1)+1, j=4..7
  const uint32_t sel = (quad >= 2) ? 0x07060302u : 0x05040100u;  // hi/lo half pick

  uint32_t ctile =
      ((uint32_t)((b * Hh + h) * SQc + qrow)) * (uint32_t)SKc + (uint32_t)(quad * 4);

  for (int kt = 0; kt < NKT; ++kt, ctile += TK) {
    // ---- S^T = K . Q^T  (3-term split: kh*qh + kl*qh + kh*ql) ----
    f32x4 s[4];
#pragma unroll
    for (int nb = 0; nb < 4; ++nb) {
      const unsigned short* kr = kh_base + ((size_t)(kt * TK + nb * 16 + lm)) * Dc + quad * 8;
      const unsigned short* krl = kl_base + ((size_t)(kt * TK + nb * 16 + lm)) * Dc + quad * 8;
      f32x4 cs = {0.f, 0.f, 0.f, 0.f};
#pragma unroll
      for (int c = 0; c < 2; ++c) {
        short8 khf = *(const short8*)(kr + c * 32);
        short8 klf = *(const short8*)(krl + c * 32);
        cs = __builtin_amdgcn_mfma_f32_16x16x32_bf16(khf, qh[c], cs, 0, 0, 0);
        cs = __builtin_amdgcn_mfma_f32_16x16x32_bf16(klf, qh[c], cs, 0, 0, 0);
        cs = __builtin_amdgcn_mfma_f32_16x16x32_bf16(khf, ql[c], cs, 0, 0, 0);
      }
      s[nb] = cs;  // S^T[sk=nb*16+quad*4+r][q=lm]
    }

    // ---- online softmax for q-row lm (reduce over sk: local16 + 2 shuffles) ----
    float mloc = -INFINITY;
#pragma unroll
    for (int nb = 0; nb < 4; ++nb)
#pragma unroll
      for (int r = 0; r < 4; ++r) mloc = fmaxf(mloc, s[nb][r]);
    mloc = fmaxf(mloc, __shfl_xor(mloc, 16));
    mloc = fmaxf(mloc, __shfl_xor(mloc, 32));
    float mnew = fmaxf(m_i, mloc);
    float alpha = __expf(m_i - mnew);
    float p32[4][4];
    float rs = 0.f;
#pragma unroll
    for (int nb = 0; nb < 4; ++nb)
#pragma unroll
      for (int r = 0; r < 4; ++r) {
        p32[nb][r] = __expf(s[nb][r] - mnew);
        rs += p32[nb][r];
      }
    rs += __shfl_xor(rs, 16);
    rs += __shfl_xor(rs, 32);
    l_i = l_i * alpha + rs;  // denominator over UNdropped probs
    m_i = mnew;
#pragma unroll
    for (int nb = 0; nb < 4; ++nb)
#pragma unroll
      for (int r = 0; r < 4; ++r) acc[nb][r] *= alpha;

    // ---- dropout (threefry) + pack bf16 pairs (nb=2g lo | nb=2g+1 hi) ----
    uint32_t pk[2][4];
#pragma unroll
    for (int g = 0; g < 2; ++g)
#pragma unroll
      for (int r = 0; r < 4; ++r) {
        uint32_t b0 = tf_bits(ctile + (uint32_t)(g * 32 + r));
        uint32_t b1 = tf_bits(ctile + (uint32_t)(g * 32 + 16 + r));
        float v0 = (b0 < 0xE6666600u) ? p32[2 * g][r] : 0.f;
        float v1 = (b1 < 0xE6666600u) ? p32[2 * g + 1][r] : 0.f;
        pk[g][r] = (f2bf_u(v1) << 16) | f2bf_u(v0);
      }

    // ---- P^T B-frags via cross-quad bpermute (no LDS tile, no barrier) ----
    short8 pb[2];
#pragma unroll
    for (int c = 0; c < 2; ++c) {
      uint32_t s0 = (uint32_t)__builtin_amdgcn_ds_bpermute(a0, (int)pk[c][0]);
      uint32_t s1 = (uint32_t)__builtin_amdgcn_ds_bpermute(a0, (int)pk[c][1]);
      uint32_t s2 = (uint32_t)__builtin_amdgcn_ds_bpermute(a0, (int)pk[c][2]);
      uint32_t s3 = (uint32_t)__builtin_amdgcn_ds_bpermute(a0, (int)pk[c][3]);
      uint32_t t0 = (uint32_t)__builtin_amdgcn_ds_bpermute(a1, (int)pk[c][0]);
      uint32_t t1 = (uint32_t)__builtin_amdgcn_ds_bpermute(a1, (int)pk[c][1]);
      uint32_t t2 = (uint32_t)__builtin_amdgcn_ds_bpermute(a1, (int)pk[c][2]);
      uint32_t t3 = (uint32_t)__builtin_amdgcn_ds_bpermute(a1, (int)pk[c][3]);
      uint32_t w0 = __builtin_amdgcn_perm(s1, s0, sel);  // (j1<<16)|j0
      uint32_t w1 = __builtin_amdgcn_perm(s3, s2, sel);  // (j3<<16)|j2
      uint32_t w2 = __builtin_amdgcn_perm(t1, t0, sel);  // (j5<<16)|j4
      uint32_t w3 = __builtin_amdgcn_perm(t3, t2, sel);  // (j7<<16)|j6
      uint32_t tmp[4] = {w0, w1, w2, w3};
      pb[c] = *(const short8*)tmp;  // B[k=quad*8+j][n=lm] for sk-chunk c
    }

    // ---- O^T += V^T . P^T ----
#pragma unroll
    for (int nb = 0; nb < 4; ++nb) {
      const unsigned short* vr =
          vt_base + ((size_t)(nb * 16 + lm)) * SKc + kt * TK + quad * 8;
      short8 vb0 = *(const short8*)(vr);
      short8 vb1 = *(const short8*)(vr + 32);
      acc[nb] = __builtin_amdgcn_mfma_f32_16x16x32_bf16(vb0, pb[0], acc[nb], 0, 0, 0);
      acc[nb] = __builtin_amdgcn_mfma_f32_16x16x32_bf16(vb1, pb[1], acc[nb], 0, 0, 0);
    }
  }

  // ---- epilogue: out[q=qrow][dv=nb*16+quad*4+r] = acc * (0.5/0.9)/l ----
  float sc = (0.5f / 0.9f) / l_i;
  float* op = out + (((size_t)(b * Hh + h)) * SQc + qrow) * DVc;
#pragma unroll
  for (int nb = 0; nb < 4; ++nb) {
    float4 o = make_float4(acc[nb][0] * sc, acc[nb][1] * sc,
                           acc[nb][2] * sc, acc[nb][3] * sc);
    *(float4*)(op + nb * 16 + quad * 4) = o;
  }
}

extern "C" void kernel_launch(void* const* d_in, const int* in_sizes, int n_in,
                              void* d_out, int out_size, void* d_ws, size_t ws_size,
                              hipStream_t stream) {
  const float* q = (const float*)d_in[0];
  const float* k = (const float*)d_in[1];
  const float* v = (const float*)d_in[2];
  float* out = (float*)d_out;
  // ws layout: Kh (4 MB) | Kl (4 MB) | Vt (4 MB)  = 12 MB total
  unsigned short* Khg = (unsigned short*)d_ws;
  unsigned short* Klg = Khg + (size_t)Hh * SKc * Dc;
  unsigned short* Vtg = Klg + (size_t)Hh * SKc * Dc;
  prep_kernel<<<dim3(Hh * 32), 256, 0, stream>>>(k, v, Khg, Klg, Vtg);
  attn_main<<<dim3(Bb * Hh * (SQc / TQ)), 256, 0, stream>>>(q, Khg, Klg, Vtg, out);
}